// Round 1
// baseline (158.713 us; speedup 1.0000x reference)
//
#include <hip/hip_runtime.h>
#include <math.h>

// Problem constants (fixed by setup_inputs)
#define T_TOKENS 32768
#define HID      4096
#define NEXP     16
#define MT       4        // tokens per wave; MT*NEXP must == 64 (wave size)

// One wave handles MT=4 tokens. Lanes split the hidden dim (float4 strides).
// acc is flat [MT*NEXP]=64 partials per lane; a halving butterfly reduce
// leaves lane l owning the full logit for (token l>>4, expert l&15).
__global__ __launch_bounds__(256) void moe_gate_kernel(
    const float* __restrict__ h,   // [T, HID]
    const float* __restrict__ w,   // [NEXP, HID]
    float* __restrict__ out)       // [2*T] indices (as float), then [2*T] weights
{
    const int lane  = threadIdx.x & 63;
    const int wv    = threadIdx.x >> 6;            // wave id in block (0..3)
    const int wtile = blockIdx.x * 4 + wv;         // global wave-tile
    const int t0    = wtile * MT;                  // first token of this wave

    float acc[MT * NEXP];
    #pragma unroll
    for (int i = 0; i < MT * NEXP; ++i) acc[i] = 0.0f;

    const int D4 = HID / 4;                        // 1024 float4 per row
    const float4* __restrict__ w4base = reinterpret_cast<const float4*>(w);

    for (int k = 0; k < D4; k += 64) {
        const int d4 = k + lane;
        float4 hv[MT];
        #pragma unroll
        for (int t = 0; t < MT; ++t) {
            const float4* hrow = reinterpret_cast<const float4*>(h + (size_t)(t0 + t) * HID);
            hv[t] = hrow[d4];
        }
        #pragma unroll
        for (int e = 0; e < NEXP; ++e) {
            float4 wvv = w4base[(size_t)e * D4 + d4];
            #pragma unroll
            for (int t = 0; t < MT; ++t) {
                float a = acc[t * NEXP + e];
                a = fmaf(hv[t].x, wvv.x, a);
                a = fmaf(hv[t].y, wvv.y, a);
                a = fmaf(hv[t].z, wvv.z, a);
                a = fmaf(hv[t].w, wvv.w, a);
                acc[t * NEXP + e] = a;
            }
        }
    }

    // Halving butterfly reduce: 64 accumulators across 64 lanes -> lane l
    // ends with the total for flat index l. 63 shuffles total.
    #pragma unroll
    for (int b = 32; b >= 1; b >>= 1) {
        const bool hi = (lane & b) != 0;
        #pragma unroll
        for (int j = 0; j < b; ++j) {
            float lo_v = acc[j];
            float hi_v = acc[j + b];
            float keepv = hi ? hi_v : lo_v;   // compile-time indices only
            float sendv = hi ? lo_v : hi_v;
            acc[j] = keepv + __shfl_xor(sendv, b, 64);
        }
    }
    const float logit = acc[0];                    // logit[t0 + (lane>>4)][lane&15]

    // Top-2 within each 16-lane group (one token per group).
    const int eidx = lane & 15;
    float m1 = logit; int i1 = eidx;
    #pragma unroll
    for (int s = 1; s < 16; s <<= 1) {
        float ov = __shfl_xor(m1, s, 64);
        int   oi = __shfl_xor(i1, s, 64);
        if (ov > m1 || (ov == m1 && oi < i1)) { m1 = ov; i1 = oi; }
    }
    float masked = (eidx == i1) ? -INFINITY : logit;
    float m2 = masked; int i2 = eidx;
    #pragma unroll
    for (int s = 1; s < 16; s <<= 1) {
        float ov = __shfl_xor(m2, s, 64);
        int   oi = __shfl_xor(i2, s, 64);
        if (ov > m2 || (ov == m2 && oi < i2)) { m2 = ov; i2 = oi; }
    }

    if (eidx == 0) {
        const int t = t0 + (lane >> 4);
        // softmax denom cancels in the renormalization:
        // w1 = g1/(g1+g2) = 1/(1+e^(l2-l1)); l2-l1 <= 0 so no overflow.
        const float r  = expf(m2 - m1);
        const float s  = 1.0f / (1.0f + r);
        const float w1 = s;
        const float w2 = r * s;
        float2* oidx = reinterpret_cast<float2*>(out);
        float2* owt  = reinterpret_cast<float2*>(out + 2 * T_TOKENS);
        oidx[t] = make_float2((float)i1, (float)i2);
        owt[t]  = make_float2(w1, w2);
    }
}

extern "C" void kernel_launch(void* const* d_in, const int* in_sizes, int n_in,
                              void* d_out, int out_size, void* d_ws, size_t ws_size,
                              hipStream_t stream) {
    const float* h = (const float*)d_in[0];   // hidden_states [32768, 4096] f32
    const float* w = (const float*)d_in[1];   // wg_weight [16, 4096] f32
    float* out = (float*)d_out;               // [65536 idx-as-f32][65536 weights]

    const int wave_tiles = T_TOKENS / MT;     // 8192 waves
    const int blocks = wave_tiles / 4;        // 4 waves per block -> 2048 blocks
    moe_gate_kernel<<<blocks, 256, 0, stream>>>(h, w, out);
}

// Round 2
// 122.212 us; speedup vs baseline: 1.2987x; 1.2987x over previous
//
#include <hip/hip_runtime.h>
#include <math.h>

// Problem constants (fixed by setup_inputs)
#define T_TOKENS 32768
#define HID      4096
#define NEXP     16
#define MT       4        // tokens per wave; MT*NEXP must == 64 (wave size)
#define WAVES    4        // waves per block
#define D4       (HID / 4)   // 1024 float4 per row
#define KI       (D4 / 64)   // 16 k-iterations

// One wave handles MT=4 tokens; a block handles 16 tokens.
// Per k-iteration the block stages the 16KiB w-tile (16 experts x 64 float4)
// into LDS once (global_load_lds, double-buffered), shared by all 4 waves.
// h is streamed with a one-iteration register prefetch.
__global__ __launch_bounds__(256) void moe_gate_kernel(
    const float* __restrict__ h,   // [T, HID]
    const float* __restrict__ w,   // [NEXP, HID]
    float* __restrict__ out)       // [2*T] indices (as float), then [2*T] weights
{
    __shared__ float4 sw[2][NEXP][64];             // 32 KiB, double-buffered

    const int lane  = threadIdx.x & 63;
    const int wv    = threadIdx.x >> 6;            // wave id in block (0..3)
    const int t0    = (blockIdx.x * WAVES + wv) * MT;

    const float4* __restrict__ w4base = reinterpret_cast<const float4*>(w);
    const float4* hrow[MT];
    #pragma unroll
    for (int t = 0; t < MT; ++t)
        hrow[t] = reinterpret_cast<const float4*>(h + (size_t)(t0 + t) * HID);

    float acc[MT * NEXP];
    #pragma unroll
    for (int i = 0; i < MT * NEXP; ++i) acc[i] = 0.0f;

    // Stage w-tile for iteration `ki` into buffer `b`.
    // Wave wv stages experts wv*4 .. wv*4+3: LDS dest is the wave-uniform row
    // base (HW places lane i at base + i*16); global src is per-lane.
#define STAGE(b, ki) do {                                                     \
        _Pragma("unroll")                                                     \
        for (int j = 0; j < 4; ++j) {                                         \
            const int e = wv * 4 + j;                                         \
            const float4* gsrc = w4base + (size_t)e * D4 + (ki) * 64 + lane;  \
            __builtin_amdgcn_global_load_lds(                                 \
                (const __attribute__((address_space(1))) void*)gsrc,          \
                (__attribute__((address_space(3))) void*)&sw[b][e][0],        \
                16, 0, 0);                                                    \
        }                                                                     \
    } while (0)

    // Prologue: stage tile 0, prefetch h for iteration 0.
    STAGE(0, 0);
    float4 hv[MT];
    #pragma unroll
    for (int t = 0; t < MT; ++t) hv[t] = hrow[t][lane];
    __syncthreads();

    int buf = 0;
    for (int ki = 0; ki < KI; ++ki) {
        // Prefetch next: w-tile into other LDS buffer, h into registers.
        float4 hn[MT];
        if (ki + 1 < KI) {
            STAGE(buf ^ 1, ki + 1);
            const int d4n = (ki + 1) * 64 + lane;
            #pragma unroll
            for (int t = 0; t < MT; ++t) hn[t] = hrow[t][d4n];
        }

        // Compute on current tile (w from LDS, h from registers).
        #pragma unroll
        for (int e = 0; e < NEXP; ++e) {
            float4 wvv = sw[buf][e][lane];
            #pragma unroll
            for (int t = 0; t < MT; ++t) {
                float a = acc[t * NEXP + e];
                a = fmaf(hv[t].x, wvv.x, a);
                a = fmaf(hv[t].y, wvv.y, a);
                a = fmaf(hv[t].z, wvv.z, a);
                a = fmaf(hv[t].w, wvv.w, a);
                acc[t * NEXP + e] = a;
            }
        }

        // One barrier/iter: makes stage(ki+1) visible AND protects buf from
        // being overwritten (next iter stages into the buffer just read).
        __syncthreads();
        buf ^= 1;
        #pragma unroll
        for (int t = 0; t < MT; ++t) hv[t] = hn[t];
    }

    // Halving butterfly reduce: 64 accumulators across 64 lanes -> lane l
    // ends with the total for flat index l (token lane>>4, expert lane&15).
    #pragma unroll
    for (int b = 32; b >= 1; b >>= 1) {
        const bool hi = (lane & b) != 0;
        #pragma unroll
        for (int j = 0; j < b; ++j) {
            float lo_v = acc[j];
            float hi_v = acc[j + b];
            float keepv = hi ? hi_v : lo_v;   // compile-time indices only
            float sendv = hi ? lo_v : hi_v;
            acc[j] = keepv + __shfl_xor(sendv, b, 64);
        }
    }
    const float logit = acc[0];

    // Top-2 within each 16-lane group (one token per group), tie-break low idx.
    const int eidx = lane & 15;
    float m1 = logit; int i1 = eidx;
    #pragma unroll
    for (int s = 1; s < 16; s <<= 1) {
        float ov = __shfl_xor(m1, s, 64);
        int   oi = __shfl_xor(i1, s, 64);
        if (ov > m1 || (ov == m1 && oi < i1)) { m1 = ov; i1 = oi; }
    }
    float masked = (eidx == i1) ? -INFINITY : logit;
    float m2 = masked; int i2 = eidx;
    #pragma unroll
    for (int s = 1; s < 16; s <<= 1) {
        float ov = __shfl_xor(m2, s, 64);
        int   oi = __shfl_xor(i2, s, 64);
        if (ov > m2 || (ov == m2 && oi < i2)) { m2 = ov; i2 = oi; }
    }

    if (eidx == 0) {
        const int t = t0 + (lane >> 4);
        // softmax denom cancels in the renormalization:
        // w1 = g1/(g1+g2) = 1/(1+e^(l2-l1)); l2-l1 <= 0 so no overflow.
        const float r  = expf(m2 - m1);
        const float s  = 1.0f / (1.0f + r);
        float2* oidx = reinterpret_cast<float2*>(out);
        float2* owt  = reinterpret_cast<float2*>(out + 2 * T_TOKENS);
        oidx[t] = make_float2((float)i1, (float)i2);
        owt[t]  = make_float2(s, r * s);
    }
#undef STAGE
}

extern "C" void kernel_launch(void* const* d_in, const int* in_sizes, int n_in,
                              void* d_out, int out_size, void* d_ws, size_t ws_size,
                              hipStream_t stream) {
    const float* h = (const float*)d_in[0];   // hidden_states [32768, 4096] f32
    const float* w = (const float*)d_in[1];   // wg_weight [16, 4096] f32
    float* out = (float*)d_out;               // [65536 idx-as-f32][65536 weights]

    const int blocks = T_TOKENS / (MT * WAVES);   // 2048 blocks, 256 thr
    moe_gate_kernel<<<blocks, 256, 0, stream>>>(h, w, out);
}

// Round 3
// 118.018 us; speedup vs baseline: 1.3448x; 1.0355x over previous
//
#include <hip/hip_runtime.h>
#include <math.h>

// Problem constants (fixed by setup_inputs)
#define T_TOKENS 32768
#define HID      4096
#define NEXP     16
#define MT       4        // tokens per wave; MT*NEXP == 64 (wave size)
#define WAVES    4        // waves per block
#define D4       (HID / 4)   // 1024 float4 per row
#define KI       (D4 / 64)   // 16 k-iterations

typedef float f32x4 __attribute__((ext_vector_type(4)));

// One wave handles MT=4 tokens; a block handles 16 tokens.
// Triple-buffered LDS w-tiles + counted vmcnt (never drain to 0 in the main
// loop) so stage/h loads stay in flight across raw s_barriers (T3/T4).
__global__ __launch_bounds__(256) void moe_gate_kernel(
    const float* __restrict__ h,   // [T, HID]
    const float* __restrict__ w,   // [NEXP, HID]
    float* __restrict__ out)       // [2*T] indices (as float), then [2*T] weights
{
    __shared__ f32x4 sw[3][NEXP][64];              // 48 KiB, triple-buffered

    const int lane = threadIdx.x & 63;
    const int wv   = threadIdx.x >> 6;             // wave id (0..3)
    const int t0   = (blockIdx.x * WAVES + wv) * MT;

    const f32x4* __restrict__ w4 = reinterpret_cast<const f32x4*>(w);
    const f32x4* hrow[MT];
    #pragma unroll
    for (int t = 0; t < MT; ++t)
        hrow[t] = reinterpret_cast<const f32x4*>(h + (size_t)(t0 + t) * HID);

    float acc[MT * NEXP];
    #pragma unroll
    for (int i = 0; i < MT * NEXP; ++i) acc[i] = 0.0f;

    // Wave wv stages experts wv*4..wv*4+3 for iteration ki_ into buffer b.
    // LDS dest = wave-uniform row base (HW: lane i -> base + i*16).
#define STAGE(b, ki_) do {                                                    \
        _Pragma("unroll")                                                     \
        for (int j = 0; j < 4; ++j) {                                         \
            const int e_ = wv * 4 + j;                                        \
            const f32x4* gsrc = w4 + (size_t)e_ * D4 + (ki_) * 64 + lane;     \
            __builtin_amdgcn_global_load_lds(                                 \
                (const __attribute__((address_space(1))) void*)gsrc,          \
                (__attribute__((address_space(3))) void*)&sw[b][e_][0],       \
                16, 0, 0);                                                    \
        }                                                                     \
    } while (0)

#define LOADH(dst, ki_) do {                                                  \
        const int d4_ = (ki_) * 64 + lane;                                    \
        _Pragma("unroll")                                                     \
        for (int t = 0; t < MT; ++t)                                          \
            dst[t] = __builtin_nontemporal_load(&hrow[t][d4_]);               \
    } while (0)

#define COMPUTE(b, hreg) do {                                                 \
        _Pragma("unroll")                                                     \
        for (int e_ = 0; e_ < NEXP; ++e_) {                                   \
            f32x4 wvv = sw[b][e_][lane];                                      \
            _Pragma("unroll")                                                 \
            for (int t = 0; t < MT; ++t) {                                    \
                float a = acc[t * NEXP + e_];                                 \
                a = fmaf(hreg[t][0], wvv[0], a);                              \
                a = fmaf(hreg[t][1], wvv[1], a);                              \
                a = fmaf(hreg[t][2], wvv[2], a);                              \
                a = fmaf(hreg[t][3], wvv[3], a);                              \
                acc[t * NEXP + e_] = a;                                       \
            }                                                                 \
        }                                                                     \
    } while (0)

    // Prologue: stage tiles 0,1; load h(0),h(1). vmcnt(4) keeps only the 4
    // newest in flight -> S0 (first-issued builtin) is guaranteed drained.
    f32x4 hv[MT], hn[MT];
    STAGE(0, 0);
    LOADH(hv, 0);
    STAGE(1, 1);
    LOADH(hn, 1);
    asm volatile("s_waitcnt vmcnt(4)" ::: "memory");
    __builtin_amdgcn_s_barrier();
    asm volatile("" ::: "memory");
    __builtin_amdgcn_sched_barrier(0);

    // Main loop: iterations 0..KI-3. Steady state: 8 loads in flight across
    // each barrier ({S(ki+2), h(ki+2)}); vmcnt(8) drains {S(ki+1), h(ki+1)}.
    // The "memory" clobbers bracket each iteration so compiler-scheduled h
    // loads cannot migrate across them -> the count is deterministic.
    int cur = 0;
    for (int ki = 0; ki < KI - 2; ++ki) {
        const int stg = (cur >= 1) ? cur - 1 : cur + 2;   // (cur+2)%3
        STAGE(stg, ki + 2);
        f32x4 h2[MT];
        LOADH(h2, ki + 2);
        COMPUTE(cur, hv);
        #pragma unroll
        for (int t = 0; t < MT; ++t) { hv[t] = hn[t]; hn[t] = h2[t]; }
        asm volatile("s_waitcnt vmcnt(8)" ::: "memory");
        __builtin_amdgcn_s_barrier();
        asm volatile("" ::: "memory");
        __builtin_amdgcn_sched_barrier(0);
        cur = (cur >= 2) ? 0 : cur + 1;
    }

    // Tail: iterations KI-2, KI-1. One full drain (cheap, once per block).
    COMPUTE(cur, hv);
    asm volatile("s_waitcnt vmcnt(0)" ::: "memory");
    __builtin_amdgcn_s_barrier();
    asm volatile("" ::: "memory");
    __builtin_amdgcn_sched_barrier(0);
    cur = (cur >= 2) ? 0 : cur + 1;
    COMPUTE(cur, hn);

    // Halving butterfly: 64 accumulators across 64 lanes -> lane l owns the
    // full logit for flat index l (token lane>>4, expert lane&15).
    #pragma unroll
    for (int b = 32; b >= 1; b >>= 1) {
        const bool hi = (lane & b) != 0;
        #pragma unroll
        for (int j = 0; j < b; ++j) {
            float lo_v = acc[j];
            float hi_v = acc[j + b];
            float keepv = hi ? hi_v : lo_v;   // compile-time indices only
            float sendv = hi ? lo_v : hi_v;
            acc[j] = keepv + __shfl_xor(sendv, b, 64);
        }
    }
    const float logit = acc[0];

    // Top-2 within each 16-lane group, tie-break low index (lax.top_k order).
    const int eidx = lane & 15;
    float m1 = logit; int i1 = eidx;
    #pragma unroll
    for (int s = 1; s < 16; s <<= 1) {
        float ov = __shfl_xor(m1, s, 64);
        int   oi = __shfl_xor(i1, s, 64);
        if (ov > m1 || (ov == m1 && oi < i1)) { m1 = ov; i1 = oi; }
    }
    float masked = (eidx == i1) ? -INFINITY : logit;
    float m2 = masked; int i2 = eidx;
    #pragma unroll
    for (int s = 1; s < 16; s <<= 1) {
        float ov = __shfl_xor(m2, s, 64);
        int   oi = __shfl_xor(i2, s, 64);
        if (ov > m2 || (ov == m2 && oi < i2)) { m2 = ov; i2 = oi; }
    }

    if (eidx == 0) {
        const int t = t0 + (lane >> 4);
        // softmax denom cancels in renorm: w1 = 1/(1+e^(l2-l1)), l2-l1 <= 0.
        const float r  = expf(m2 - m1);
        const float s  = 1.0f / (1.0f + r);
        float2* oidx = reinterpret_cast<float2*>(out);
        float2* owt  = reinterpret_cast<float2*>(out + 2 * T_TOKENS);
        oidx[t] = make_float2((float)i1, (float)i2);
        owt[t]  = make_float2(s, r * s);
    }
#undef STAGE
#undef LOADH
#undef COMPUTE
}

extern "C" void kernel_launch(void* const* d_in, const int* in_sizes, int n_in,
                              void* d_out, int out_size, void* d_ws, size_t ws_size,
                              hipStream_t stream) {
    const float* h = (const float*)d_in[0];   // hidden_states [32768, 4096] f32
    const float* w = (const float*)d_in[1];   // wg_weight [16, 4096] f32
    float* out = (float*)d_out;               // [65536 idx-as-f32][65536 weights]

    const int blocks = T_TOKENS / (MT * WAVES);   // 2048 blocks, 256 thr
    moe_gate_kernel<<<blocks, 256, 0, stream>>>(h, w, out);
}

// Round 4
// 117.893 us; speedup vs baseline: 1.3462x; 1.0011x over previous
//
#include <hip/hip_runtime.h>
#include <math.h>

// Problem constants (fixed by setup_inputs)
#define T_TOKENS 32768
#define HID      4096
#define NEXP     16
#define MT       8        // tokens per wave (acc = MT*NEXP = 128/lane)
#define WAVES    4        // waves per block -> 32 tokens/block
#define D4       (HID / 4)   // 1024 float4 per row
#define KI       (D4 / 64)   // 16 k-iterations

typedef float f32x4 __attribute__((ext_vector_type(4)));

// One wave handles MT=8 tokens; block stages the 16KiB w-tile once per iter
// (double-buffered LDS, global_load_lds). Each staged tile now serves 8
// tokens/wave -> LDS read amplification halved vs MT=4. Counted vmcnt keeps
// the 8 h-loads in flight across each barrier.
__global__ __launch_bounds__(256, 2) void moe_gate_kernel(
    const float* __restrict__ h,   // [T, HID]
    const float* __restrict__ w,   // [NEXP, HID]
    float* __restrict__ out)       // [2*T] indices (as float), then [2*T] weights
{
    __shared__ f32x4 sw[2][NEXP][64];              // 32 KiB double-buffered

    const int lane = threadIdx.x & 63;
    const int wv   = threadIdx.x >> 6;             // wave id (0..3)
    const int t0   = (blockIdx.x * WAVES + wv) * MT;

    const f32x4* __restrict__ w4 = reinterpret_cast<const f32x4*>(w);
    const f32x4* hrow[MT];
    #pragma unroll
    for (int t = 0; t < MT; ++t)
        hrow[t] = reinterpret_cast<const f32x4*>(h + (size_t)(t0 + t) * HID);

    float acc[MT * NEXP];
    #pragma unroll
    for (int i = 0; i < MT * NEXP; ++i) acc[i] = 0.0f;

    // Wave wv stages experts wv*4..wv*4+3 for iteration ki_ into buffer b.
#define STAGE(b, ki_) do {                                                    \
        _Pragma("unroll")                                                     \
        for (int j = 0; j < 4; ++j) {                                         \
            const int e_ = wv * 4 + j;                                        \
            const f32x4* gsrc = w4 + (size_t)e_ * D4 + (ki_) * 64 + lane;     \
            __builtin_amdgcn_global_load_lds(                                 \
                (const __attribute__((address_space(1))) void*)gsrc,          \
                (__attribute__((address_space(3))) void*)&sw[b][e_][0],       \
                16, 0, 0);                                                    \
        }                                                                     \
    } while (0)

#define LOADH(dst, ki_) do {                                                  \
        const int d4_ = (ki_) * 64 + lane;                                    \
        _Pragma("unroll")                                                     \
        for (int t = 0; t < MT; ++t)                                          \
            dst[t] = __builtin_nontemporal_load(&hrow[t][d4_]);               \
    } while (0)

#define COMPUTE(b, hreg) do {                                                 \
        _Pragma("unroll")                                                     \
        for (int e_ = 0; e_ < NEXP; ++e_) {                                   \
            f32x4 wvv = sw[b][e_][lane];                                      \
            _Pragma("unroll")                                                 \
            for (int t = 0; t < MT; ++t) {                                    \
                float a = acc[t * NEXP + e_];                                 \
                a = fmaf(hreg[t][0], wvv[0], a);                              \
                a = fmaf(hreg[t][1], wvv[1], a);                              \
                a = fmaf(hreg[t][2], wvv[2], a);                              \
                a = fmaf(hreg[t][3], wvv[3], a);                              \
                acc[t * NEXP + e_] = a;                                       \
            }                                                                 \
        }                                                                     \
    } while (0)

    // Prologue: stage tile 0 (4 loads) + h(0) (8 loads). vmcnt(8) drains the
    // stage (oldest 4), leaves h(0) in flight (compiler waits before its use).
    f32x4 hv[MT];
    STAGE(0, 0);
    LOADH(hv, 0);
    asm volatile("s_waitcnt vmcnt(8)" ::: "memory");
    __builtin_amdgcn_s_barrier();
    asm volatile("" ::: "memory");
    __builtin_amdgcn_sched_barrier(0);

    // Main loop. Steady state at the barrier: h(ki+1)'s 8 loads stay in
    // flight; vmcnt(8) drains S(ki+1) (issued before them). "memory" brackets
    // keep compiler-scheduled loads inside their iteration -> count is exact.
    int cur = 0;
    for (int ki = 0; ki < KI - 1; ++ki) {
        STAGE(cur ^ 1, ki + 1);
        f32x4 hn[MT];
        LOADH(hn, ki + 1);
        COMPUTE(cur, hv);
        #pragma unroll
        for (int t = 0; t < MT; ++t) hv[t] = hn[t];
        asm volatile("s_waitcnt vmcnt(8)" ::: "memory");
        __builtin_amdgcn_s_barrier();
        asm volatile("" ::: "memory");
        __builtin_amdgcn_sched_barrier(0);
        cur ^= 1;
    }
    COMPUTE(cur, hv);   // last tile; epilogue is register-only, no barrier

    // Two halving butterflies: acc[base..base+63] across 64 lanes -> lane l
    // owns flat index base+l, where flat = t*16+e (t = base/64*4 + (l>>4)).
#define BUTTERFLY(base) do {                                                  \
        _Pragma("unroll")                                                     \
        for (int b = 32; b >= 1; b >>= 1) {                                   \
            const bool hi_ = (lane & b) != 0;                                 \
            _Pragma("unroll")                                                 \
            for (int j = 0; j < b; ++j) {                                     \
                float lo_v = acc[(base) + j];                                 \
                float hi_v = acc[(base) + j + b];                             \
                float keepv = hi_ ? hi_v : lo_v;                              \
                float sendv = hi_ ? lo_v : hi_v;                              \
                acc[(base) + j] = keepv + __shfl_xor(sendv, b, 64);           \
            }                                                                 \
        }                                                                     \
    } while (0)

    BUTTERFLY(0);
    BUTTERFLY(64);
    const float logit0 = acc[0];    // token t0 + (lane>>4),     expert lane&15
    const float logit1 = acc[64];   // token t0 + 4 + (lane>>4), expert lane&15

    // Top-2 within each 16-lane group, tie-break low index (lax.top_k order).
    const int eidx = lane & 15;
#define TOP2_WRITE(logit_, tok_) do {                                         \
        float m1 = (logit_); int i1 = eidx;                                   \
        _Pragma("unroll")                                                     \
        for (int s = 1; s < 16; s <<= 1) {                                    \
            float ov = __shfl_xor(m1, s, 64);                                 \
            int   oi = __shfl_xor(i1, s, 64);                                 \
            if (ov > m1 || (ov == m1 && oi < i1)) { m1 = ov; i1 = oi; }       \
        }                                                                     \
        float masked = (eidx == i1) ? -INFINITY : (logit_);                   \
        float m2 = masked; int i2 = eidx;                                     \
        _Pragma("unroll")                                                     \
        for (int s = 1; s < 16; s <<= 1) {                                    \
            float ov = __shfl_xor(m2, s, 64);                                 \
            int   oi = __shfl_xor(i2, s, 64);                                 \
            if (ov > m2 || (ov == m2 && oi < i2)) { m2 = ov; i2 = oi; }       \
        }                                                                     \
        if (eidx == 0) {                                                      \
            const float r_ = expf(m2 - m1);                                   \
            const float s_ = 1.0f / (1.0f + r_);                              \
            float2* oidx = reinterpret_cast<float2*>(out);                    \
            float2* owt  = reinterpret_cast<float2*>(out + 2 * T_TOKENS);     \
            oidx[tok_] = make_float2((float)i1, (float)i2);                   \
            owt[tok_]  = make_float2(s_, r_ * s_);                            \
        }                                                                     \
    } while (0)

    TOP2_WRITE(logit0, t0 + (lane >> 4));
    TOP2_WRITE(logit1, t0 + 4 + (lane >> 4));

#undef STAGE
#undef LOADH
#undef COMPUTE
#undef BUTTERFLY
#undef TOP2_WRITE
}

extern "C" void kernel_launch(void* const* d_in, const int* in_sizes, int n_in,
                              void* d_out, int out_size, void* d_ws, size_t ws_size,
                              hipStream_t stream) {
    const float* h = (const float*)d_in[0];   // hidden_states [32768, 4096] f32
    const float* w = (const float*)d_in[1];   // wg_weight [16, 4096] f32
    float* out = (float*)d_out;               // [65536 idx-as-f32][65536 weights]

    const int blocks = T_TOKENS / (MT * WAVES);   // 1024 blocks, 256 thr
    moe_gate_kernel<<<blocks, 256, 0, stream>>>(h, w, out);
}

// Round 5
// 112.870 us; speedup vs baseline: 1.4062x; 1.0445x over previous
//
#include <hip/hip_runtime.h>
#include <math.h>

// Problem constants (fixed by setup_inputs)
#define T_TOKENS 32768
#define HID      4096
#define NEXP     16
#define MT       8            // tokens per wave
#define WAVES    8            // waves per block -> 64 tokens/block
#define D4       (HID / 4)    // 1024 f32x4 per row
#define HALF     (D4 / 2)     // 512 f32x4 per half-row
#define NC       (HALF / 64)  // 8 chunk-iterations per phase

typedef float f32x4 __attribute__((ext_vector_type(4)));

// Two-phase mega-stage: LDS holds w for ALL 16 experts over half the hidden
// dim (128 KiB). Per phase, waves free-run 8 chunk-iterations with NO
// barriers/asm waits (compiler-scheduled, waves drift -> smooth HBM issue).
// Only 3 sync points per block instead of 16.
__global__ __launch_bounds__(512, 2) void moe_gate_kernel(
    const float* __restrict__ h,   // [T, HID]
    const float* __restrict__ w,   // [NEXP, HID]
    float* __restrict__ out)       // [2*T] indices (as float), then [2*T] weights
{
    __shared__ f32x4 sw[NEXP][HALF];               // 128 KiB, single-buffered

    const int lane = threadIdx.x & 63;
    const int wv   = threadIdx.x >> 6;             // wave id (0..7)
    const int t0   = blockIdx.x * (MT * WAVES) + wv * MT;

    const f32x4* __restrict__ w4 = reinterpret_cast<const f32x4*>(w);
    const f32x4* hrow[MT];
    #pragma unroll
    for (int t = 0; t < MT; ++t)
        hrow[t] = reinterpret_cast<const f32x4*>(h + (size_t)(t0 + t) * HID);

    float acc[MT * NEXP];
    #pragma unroll
    for (int i = 0; i < MT * NEXP; ++i) acc[i] = 0.0f;

    // Wave wv stages experts 2wv,2wv+1 (8 chunks each = 16 loads of 1 KiB).
#define STAGE(kh_) do {                                                       \
        _Pragma("unroll")                                                     \
        for (int j = 0; j < 16; ++j) {                                        \
            const int e_ = 2 * wv + (j >> 3);                                 \
            const int c_ = j & 7;                                             \
            const f32x4* gsrc =                                               \
                w4 + (size_t)e_ * D4 + (kh_) * HALF + c_ * 64 + lane;         \
            __builtin_amdgcn_global_load_lds(                                 \
                (const __attribute__((address_space(1))) void*)gsrc,          \
                (__attribute__((address_space(3))) void*)&sw[e_][c_ * 64],    \
                16, 0, 0);                                                    \
        }                                                                     \
    } while (0)

#define LOADH(dst, kh_, c_) do {                                              \
        const int d4_ = (kh_) * HALF + (c_) * 64 + lane;                      \
        _Pragma("unroll")                                                     \
        for (int t = 0; t < MT; ++t)                                          \
            dst[t] = __builtin_nontemporal_load(&hrow[t][d4_]);               \
    } while (0)

#define COMPUTE(c_, hreg) do {                                                \
        _Pragma("unroll")                                                     \
        for (int e_ = 0; e_ < NEXP; ++e_) {                                   \
            f32x4 wvv = sw[e_][(c_) * 64 + lane];                             \
            _Pragma("unroll")                                                 \
            for (int t = 0; t < MT; ++t) {                                    \
                float a = acc[t * NEXP + e_];                                 \
                a = fmaf(hreg[t][0], wvv[0], a);                              \
                a = fmaf(hreg[t][1], wvv[1], a);                              \
                a = fmaf(hreg[t][2], wvv[2], a);                              \
                a = fmaf(hreg[t][3], wvv[3], a);                              \
                acc[t * NEXP + e_] = a;                                       \
            }                                                                 \
        }                                                                     \
    } while (0)

    f32x4 hv[MT], hn[MT];

    for (int kh = 0; kh < 2; ++kh) {
        if (kh) {
            // All waves must be done READING sw (phase 0) before restaging.
            // ds_reads already drained (consumed by FMAs); raw barrier only.
            asm volatile("s_waitcnt lgkmcnt(0)" ::: "memory");
            __builtin_amdgcn_s_barrier();
            asm volatile("" ::: "memory");
        }
        STAGE(kh);
        __builtin_amdgcn_sched_barrier(0);   // pin: stage strictly before h
        LOADH(hv, kh, 0);
        // outstanding: 16 stage (older) + 8 h (newer); vmcnt(8) drains the
        // stage completely while keeping h(c=0) in flight.
        asm volatile("s_waitcnt vmcnt(8)" ::: "memory");
        __builtin_amdgcn_s_barrier();
        asm volatile("" ::: "memory");
        __builtin_amdgcn_sched_barrier(0);

        // Free-running phase: no barriers, no asm waits. 1-chunk h prefetch;
        // compiler schedules loads/ds_reads/FMAs at will.
        #pragma unroll 1
        for (int c = 0; c < NC - 1; ++c) {
            LOADH(hn, kh, c + 1);
            COMPUTE(c, hv);
            #pragma unroll
            for (int t = 0; t < MT; ++t) hv[t] = hn[t];
        }
        COMPUTE(NC - 1, hv);
    }

    // Two halving butterflies: acc[base..base+63] across 64 lanes -> lane l
    // owns flat index base+l (flat = j*16+e; token j = base/64*4 + (l>>4)).
#define BUTTERFLY(base) do {                                                  \
        _Pragma("unroll")                                                     \
        for (int b = 32; b >= 1; b >>= 1) {                                   \
            const bool hi_ = (lane & b) != 0;                                 \
            _Pragma("unroll")                                                 \
            for (int j = 0; j < b; ++j) {                                     \
                float lo_v = acc[(base) + j];                                 \
                float hi_v = acc[(base) + j + b];                             \
                float keepv = hi_ ? hi_v : lo_v;                              \
                float sendv = hi_ ? lo_v : hi_v;                              \
                acc[(base) + j] = keepv + __shfl_xor(sendv, b, 64);           \
            }                                                                 \
        }                                                                     \
    } while (0)

    BUTTERFLY(0);
    BUTTERFLY(64);
    const float logit0 = acc[0];    // token t0 + (lane>>4),     expert lane&15
    const float logit1 = acc[64];   // token t0 + 4 + (lane>>4), expert lane&15

    // Top-2 within each 16-lane group, tie-break low index (lax.top_k order).
    const int eidx = lane & 15;
#define TOP2_WRITE(logit_, tok_) do {                                         \
        float m1 = (logit_); int i1 = eidx;                                   \
        _Pragma("unroll")                                                     \
        for (int s = 1; s < 16; s <<= 1) {                                    \
            float ov = __shfl_xor(m1, s, 64);                                 \
            int   oi = __shfl_xor(i1, s, 64);                                 \
            if (ov > m1 || (ov == m1 && oi < i1)) { m1 = ov; i1 = oi; }       \
        }                                                                     \
        float masked = (eidx == i1) ? -INFINITY : (logit_);                   \
        float m2 = masked; int i2 = eidx;                                     \
        _Pragma("unroll")                                                     \
        for (int s = 1; s < 16; s <<= 1) {                                    \
            float ov = __shfl_xor(m2, s, 64);                                 \
            int   oi = __shfl_xor(i2, s, 64);                                 \
            if (ov > m2 || (ov == m2 && oi < i2)) { m2 = ov; i2 = oi; }       \
        }                                                                     \
        if (eidx == 0) {                                                      \
            const float r_ = expf(m2 - m1);                                   \
            const float s_ = 1.0f / (1.0f + r_);                              \
            float2* oidx = reinterpret_cast<float2*>(out);                    \
            float2* owt  = reinterpret_cast<float2*>(out + 2 * T_TOKENS);     \
            oidx[tok_] = make_float2((float)i1, (float)i2);                   \
            owt[tok_]  = make_float2(s_, r_ * s_);                            \
        }                                                                     \
    } while (0)

    TOP2_WRITE(logit0, t0 + (lane >> 4));
    TOP2_WRITE(logit1, t0 + 4 + (lane >> 4));

#undef STAGE
#undef LOADH
#undef COMPUTE
#undef BUTTERFLY
#undef TOP2_WRITE
}

extern "C" void kernel_launch(void* const* d_in, const int* in_sizes, int n_in,
                              void* d_out, int out_size, void* d_ws, size_t ws_size,
                              hipStream_t stream) {
    const float* h = (const float*)d_in[0];   // hidden_states [32768, 4096] f32
    const float* w = (const float*)d_in[1];   // wg_weight [16, 4096] f32
    float* out = (float*)d_out;               // [65536 idx-as-f32][65536 weights]

    const int blocks = T_TOKENS / (MT * WAVES);   // 512 blocks, 512 thr
    moe_gate_kernel<<<blocks, 512, 0, stream>>>(h, w, out);
}